// Round 8
// baseline (75.782 us; speedup 1.0000x reference)
//
#include <hip/hip_runtime.h>

// RotationalConv2D R10: M-split waves (no split-K, no reduce) on the R9 base.
//  - wave wv owns M-tile wv (pixels 16wv..16wv+15) and runs the FULL K=400
//    loop itself (13 chunks x 2 taps) -> results final in-register, bias
//    preloaded into acc (R6-proven mapping), direct coalesced stores.
//  - same per-lane inner cost as R9's split-K (13 blend8h, 26 MFMA), but the
//    cross-wave reduce phase, its 2 barriers and 25KB of LDS are gone.
//  - acc 8->2 floatx4, angs 4->1 float4  => fits 128 VGPR,
//    __launch_bounds__(256,4) guarantees 4 blocks/CU.
//  - stage (f16 tile + exact-f32 partials) and algebraic angle: R9-proven.
// 2 barriers total.

#define KS     5
#define TILE   8
#define TW     (TILE + KS - 1)     // 12
#define SINH   24                  // f16 tile pixel stride (halves, 48 B)
#define C_IN   16
#define F_OUT  32
#define H_IN   128
#define W_IN   128
#define HO     124
#define WO     124
#define NBATCH 4
#define EPSF   1e-7f
#define BLOCK  256
#define KW     400                 // K = 25*16

// LDS layout (bytes): s_inh [0,6912) | s_part [6912,9216) | s_ang [9216,10240)
#define PART_OFF    6912
#define ANG_OFF     9216
#define SMEM_BYTES  10240

typedef _Float16 half8  __attribute__((ext_vector_type(8)));
typedef _Float16 half4v __attribute__((ext_vector_type(4)));
typedef __attribute__((ext_vector_type(4))) float floatx4;

// Blend 8 channels [ch0, ch0+8) of tap t for pixel (lxq, lyq) -> f16 x8.
// Weights computed in f32 (exact index math), blend in packed f16. (R8/R9-proven)
static __device__ __forceinline__ half8 blend8h(
    const _Float16* __restrict__ s_inh, int lxq, int lyq,
    float co, float si, float xo, float yo, int t, int ch0)
{
    const float scl = 1.0f / (1.0f + EPSF);
    int ky = t / KS, kx = t - KS * ky;
    float sx = (co * (float)kx - si * (float)ky + xo) * scl;
    float sy = (si * (float)kx + co * (float)ky + yo) * scl;
    float fx0 = floorf(sx), fy0 = floorf(sy);
    float wx = sx - fx0, wy = sy - fy0;
    int x0 = (int)fx0, y0 = (int)fy0;
    int x1 = x0 + 1, y1 = y0 + 1;
    float vx0 = (x0 >= 0 && x0 < KS) ? 1.f : 0.f;
    float vx1 = (x1 >= 0 && x1 < KS) ? 1.f : 0.f;
    float vy0 = (y0 >= 0 && y0 < KS) ? 1.f : 0.f;
    float vy1 = (y1 >= 0 && y1 < KS) ? 1.f : 0.f;
    float w00 = (1.f - wx) * (1.f - wy) * vx0 * vy0;
    float w01 = wx * (1.f - wy) * vx1 * vy0;
    float w10 = (1.f - wx) * wy * vx0 * vy1;
    float w11 = wx * wy * vx1 * vy1;
    int cx0 = min(max(x0, 0), KS - 1), cx1 = min(max(x1, 0), KS - 1);
    int cy0 = min(max(y0, 0), KS - 1), cy1 = min(max(y1, 0), KS - 1);
    const _Float16* p00 = &s_inh[((lyq + cy0) * TW + (lxq + cx0)) * SINH + ch0];
    const _Float16* p01 = &s_inh[((lyq + cy0) * TW + (lxq + cx1)) * SINH + ch0];
    const _Float16* p10 = &s_inh[((lyq + cy1) * TW + (lxq + cx0)) * SINH + ch0];
    const _Float16* p11 = &s_inh[((lyq + cy1) * TW + (lxq + cx1)) * SINH + ch0];
    half8 a = *(const half8*)p00;
    half8 b = *(const half8*)p01;
    half8 c = *(const half8*)p10;
    half8 d = *(const half8*)p11;
    _Float16 h00 = (_Float16)w00, h01 = (_Float16)w01;
    _Float16 h10 = (_Float16)w10, h11 = (_Float16)w11;
    half8 W00 = {h00,h00,h00,h00,h00,h00,h00,h00};
    half8 W01 = {h01,h01,h01,h01,h01,h01,h01,h01};
    half8 W10 = {h10,h10,h10,h10,h10,h10,h10,h10};
    half8 W11 = {h11,h11,h11,h11,h11,h11,h11,h11};
    return a * W00 + b * W01 + c * W10 + d * W11;
}

__global__ __launch_bounds__(BLOCK, 4) void rotconv_kernel(
    const float* __restrict__ in, const float* __restrict__ Wg,
    const float* __restrict__ bg, float* __restrict__ out)
{
    __shared__ __align__(16) char smem[SMEM_BYTES];
    _Float16* s_inh  = (_Float16*)smem;
    float*    s_part = (float*)(smem + PART_OFF);
    float4*   s_ang4 = (float4*)(smem + ANG_OFF);

    const int tid  = threadIdx.x;
    const int bx = blockIdx.x, by = blockIdx.y, bimg = blockIdx.z;
    const int ox = bx * TILE, oy = by * TILE;

    // ---- stage: f16 tile + exact-f32 channel partials, one pass (R9) ----
    const float* inb = in + (size_t)bimg * (H_IN * W_IN * C_IN);
    for (int i = tid; i < TW * TW * (C_IN / 4); i += BLOCK) {
        int cv = i & 3;
        int pp = i >> 2;
        int x = pp % TW, y = pp / TW;
        int gy = oy + y, gx = ox + x;
        float4 v = make_float4(0.f, 0.f, 0.f, 0.f);
        if (gy < H_IN && gx < W_IN)
            v = *(const float4*)(inb + ((size_t)(gy * W_IN + gx) * C_IN) + 4 * cv);
        half4v h = {(_Float16)v.x, (_Float16)v.y, (_Float16)v.z, (_Float16)v.w};
        *(half4v*)(&s_inh[pp * SINH + 4 * cv]) = h;
        s_part[pp * 4 + cv] = (v.x + v.y) + (v.z + v.w);
    }
    __syncthreads();

    // ---- angle (threads 0..63): exact-f32 intensity window, algebraic cos/sin (R9) ----
    if (tid < 64) {
        const int alx = tid & 7, aly = tid >> 3;
        float tot = EPSF, cr = 0.f, cc = 0.f;
        #pragma unroll
        for (int dy = 0; dy < KS; ++dy)
            #pragma unroll
            for (int dx = 0; dx < KS; ++dx) {
                float4 pv = *(const float4*)(&s_part[((aly + dy) * TW + (alx + dx)) * 4]);
                float v = (pv.x + pv.y) + (pv.z + pv.w);
                tot += v; cr += v * (float)dy; cc += v * (float)dx;
            }
        cr /= tot; cc /= tot;
        float dyv = cr - 2.0f, dxv = cc - 2.0f + EPSF;
        float r = sqrtf(dxv * dxv + dyv * dyv);
        float co, si;
        if (r < 1e-20f) { co = 1.f; si = 0.f; }     // atan2(0,+0) = 0
        else           { float ri = 1.0f / r; co = dxv * ri; si = dyv * ri; }
        float xoff = (4.0f - (co * 4.0f - si * 4.0f)) * 0.5f;
        float yoff = (4.0f - (si * 4.0f + co * 4.0f)) * 0.5f;
        s_ang4[tid] = make_float4(co, si, xoff, yoff);
    }
    __syncthreads();

    const int p    = tid & 63;     // lane
    const int wv   = tid >> 6;     // wave id 0..3 -> M-tile wv (pixels 16wv+..)
    const int col  = p & 15;       // MFMA lane&15: pixel-in-Mtile AND f-in-Ntile
    const int quad = p >> 4;       // MFMA lane>>4
    const int ch0  = (quad & 1) * 8;

    // this lane's pixel: 16wv+col -> tile coords
    const int lxq = col & 7;
    const int lyq = 2 * wv + (col >> 3);
    const float4 ang = s_ang4[16 * wv + col];

    // accumulators with bias preloaded (R6-proven)
    floatx4 acc0, acc1;
    {
        float bv0 = bg[col], bv1 = bg[col + 16];
        acc0 = (floatx4){bv0, bv0, bv0, bv0};
        acc1 = (floatx4){bv1, bv1, bv1, bv1};
    }

    const half8 zero8 = {0,0,0,0,0,0,0,0};

    // ---- full-K loop: 13 chunks of K=32 (2 taps); quad01 -> tap 2c, quad23 -> 2c+1
    for (int c = 0; c < 13; ++c) {
        const int tq = 2 * c + (quad >> 1);
        const bool val = (tq < KS * KS);       // false only for c=12, quads 2,3

        half8 bf0 = zero8, bf1 = zero8, av = zero8;
        if (val) {
            const float* wp0 = Wg + (size_t)col * KW + tq * 16 + ch0;
            float4 a = *(const float4*)(wp0);
            float4 b = *(const float4*)(wp0 + 4);
            bf0 = (half8){(_Float16)a.x, (_Float16)a.y, (_Float16)a.z, (_Float16)a.w,
                          (_Float16)b.x, (_Float16)b.y, (_Float16)b.z, (_Float16)b.w};
            const float* wp1 = wp0 + (size_t)16 * KW;
            float4 cc4 = *(const float4*)(wp1);
            float4 d4  = *(const float4*)(wp1 + 4);
            bf1 = (half8){(_Float16)cc4.x, (_Float16)cc4.y, (_Float16)cc4.z, (_Float16)cc4.w,
                          (_Float16)d4.x,  (_Float16)d4.y,  (_Float16)d4.z,  (_Float16)d4.w};
            av = blend8h(s_inh, lxq, lyq, ang.x, ang.y, ang.z, ang.w, tq, ch0);
        }
        acc0 = __builtin_amdgcn_mfma_f32_16x16x32_f16(av, bf0, acc0, 0, 0, 0);
        acc1 = __builtin_amdgcn_mfma_f32_16x16x32_f16(av, bf1, acc1, 0, 0, 0);
    }

    // ---- epilogue: D[pixel-in-tile = 4quad+r][f = col]; pixel = 16wv+4quad+r ----
    #pragma unroll
    for (int r = 0; r < 4; ++r) {
        const int pix = 16 * wv + 4 * quad + r;
        const int ho = oy + (pix >> 3), wo = ox + (pix & 7);
        if (ho < HO && wo < WO) {
            float* op = out + (((size_t)bimg * HO + ho) * WO + wo) * F_OUT + col;
            op[0]  = acc0[r];
            op[16] = acc1[r];
        }
    }
}

extern "C" void kernel_launch(void* const* d_in, const int* in_sizes, int n_in,
                              void* d_out, int out_size, void* d_ws, size_t ws_size,
                              hipStream_t stream) {
    const float* in = (const float*)d_in[0];
    const float* Wg = (const float*)d_in[1];
    const float* bg = (const float*)d_in[2];
    float* out      = (float*)d_out;
    dim3 grid((WO + TILE - 1) / TILE, (HO + TILE - 1) / TILE, NBATCH);
    rotconv_kernel<<<grid, dim3(BLOCK), 0, stream>>>(in, Wg, bg, out);
}

// Round 9
// 74.125 us; speedup vs baseline: 1.0223x; 1.0223x over previous
//
#include <hip/hip_runtime.h>

// RotationalConv2D R11: R9 (best, 71.5us) + W-fragment register prefetch.
//  - R10's M-split regressed (+4.2us): it broke R9's W-load amortization
//    (4 float4 -> 8 MFMAs) and its rolled loop exposed per-iteration L2
//    latency. Reverted to R9's split-K structure.
//  - NEW: all W-fragment loads (<=16 float4/lane, known from lane id alone)
//    issue as the FIRST instructions of the kernel and convert to f16 regs
//    wf[4][2] (32 VGPR, statically indexed). Their latency hides under the
//    stage + partials + angle phases. K-loop is pure LDS blend + MFMA.
// 4 barriers total.

#define KS     5
#define TILE   8
#define TW     (TILE + KS - 1)     // 12
#define SINH   24                  // f16 tile pixel stride (halves, 48 B)
#define C_IN   16
#define F_OUT  32
#define H_IN   128
#define W_IN   128
#define HO     124
#define WO     124
#define NBATCH 4
#define EPSF   1e-7f
#define BLOCK  256
#define KW     400                 // K = 25*16

// LDS layout (bytes):
//   phase 1: s_inh [0,6912) f16 tile | s_part [6912,9216) f32 partials
//            s_ang [9216,10240)
//   phase 2 (epilogue, after barrier): red [0,34816) -- aliases everything
#define PART_OFF    6912
#define ANG_OFF     9216
#define RED_STRIDE  34             // floats per pixel row (136 B)
#define RED_WAVE    (64 * RED_STRIDE)
#define SMEM_BYTES  34816

typedef _Float16 half8  __attribute__((ext_vector_type(8)));
typedef _Float16 half4v __attribute__((ext_vector_type(4)));
typedef __attribute__((ext_vector_type(4))) float floatx4;

// Blend 8 channels [ch0, ch0+8) of tap t for pixel (lxq, lyq) -> f16 x8.
// Weights computed in f32 (exact index math), blend in packed f16. (R8/R9-proven)
static __device__ __forceinline__ half8 blend8h(
    const _Float16* __restrict__ s_inh, int lxq, int lyq,
    float co, float si, float xo, float yo, int t, int ch0)
{
    const float scl = 1.0f / (1.0f + EPSF);
    int ky = t / KS, kx = t - KS * ky;
    float sx = (co * (float)kx - si * (float)ky + xo) * scl;
    float sy = (si * (float)kx + co * (float)ky + yo) * scl;
    float fx0 = floorf(sx), fy0 = floorf(sy);
    float wx = sx - fx0, wy = sy - fy0;
    int x0 = (int)fx0, y0 = (int)fy0;
    int x1 = x0 + 1, y1 = y0 + 1;
    float vx0 = (x0 >= 0 && x0 < KS) ? 1.f : 0.f;
    float vx1 = (x1 >= 0 && x1 < KS) ? 1.f : 0.f;
    float vy0 = (y0 >= 0 && y0 < KS) ? 1.f : 0.f;
    float vy1 = (y1 >= 0 && y1 < KS) ? 1.f : 0.f;
    float w00 = (1.f - wx) * (1.f - wy) * vx0 * vy0;
    float w01 = wx * (1.f - wy) * vx1 * vy0;
    float w10 = (1.f - wx) * wy * vx0 * vy1;
    float w11 = wx * wy * vx1 * vy1;
    int cx0 = min(max(x0, 0), KS - 1), cx1 = min(max(x1, 0), KS - 1);
    int cy0 = min(max(y0, 0), KS - 1), cy1 = min(max(y1, 0), KS - 1);
    const _Float16* p00 = &s_inh[((lyq + cy0) * TW + (lxq + cx0)) * SINH + ch0];
    const _Float16* p01 = &s_inh[((lyq + cy0) * TW + (lxq + cx1)) * SINH + ch0];
    const _Float16* p10 = &s_inh[((lyq + cy1) * TW + (lxq + cx0)) * SINH + ch0];
    const _Float16* p11 = &s_inh[((lyq + cy1) * TW + (lxq + cx1)) * SINH + ch0];
    half8 a = *(const half8*)p00;
    half8 b = *(const half8*)p01;
    half8 c = *(const half8*)p10;
    half8 d = *(const half8*)p11;
    _Float16 h00 = (_Float16)w00, h01 = (_Float16)w01;
    _Float16 h10 = (_Float16)w10, h11 = (_Float16)w11;
    half8 W00 = {h00,h00,h00,h00,h00,h00,h00,h00};
    half8 W01 = {h01,h01,h01,h01,h01,h01,h01,h01};
    half8 W10 = {h10,h10,h10,h10,h10,h10,h10,h10};
    half8 W11 = {h11,h11,h11,h11,h11,h11,h11,h11};
    return a * W00 + b * W01 + c * W10 + d * W11;
}

__global__ __launch_bounds__(BLOCK, 2) void rotconv_kernel(
    const float* __restrict__ in, const float* __restrict__ Wg,
    const float* __restrict__ bg, float* __restrict__ out)
{
    __shared__ __align__(16) char smem[SMEM_BYTES];
    _Float16* s_inh  = (_Float16*)smem;
    float*    s_part = (float*)(smem + PART_OFF);
    float4*   s_ang4 = (float4*)(smem + ANG_OFF);
    float*    red    = (float*)smem;           // epilogue alias

    const int tid  = threadIdx.x;
    const int bx = blockIdx.x, by = blockIdx.y, bimg = blockIdx.z;
    const int ox = bx * TILE, oy = by * TILE;

    const int p    = tid & 63;     // lane
    const int wv   = tid >> 6;     // wave id 0..3
    const int col  = p & 15;       // MFMA lane&15
    const int quad = p >> 4;       // MFMA lane>>4
    const int ch0  = (quad & 1) * 8;
    const int nstep = (wv == 0) ? 4 : 3;       // wave 0 also covers tap 24
    const half8 zero8 = {0,0,0,0,0,0,0,0};

    // ---- W-fragment PREFETCH: issue global loads FIRST, convert to f16 regs.
    // wf[s][n]: B-fragment for step s, N-tile n. Latency hides under stage+angle.
    half8 wf[4][2];
    #pragma unroll
    for (int s = 0; s < 4; ++s) {
        wf[s][0] = zero8;
        wf[s][1] = zero8;
        const int ta = wv + 8 * s;
        const int tb = ta + 4;
        const int tq = (quad < 2) ? ta : tb;
        if (s < nstep && tq < KS * KS) {
            const float* wp0 = Wg + (size_t)col * KW + tq * 16 + ch0;
            float4 a = *(const float4*)(wp0);
            float4 b = *(const float4*)(wp0 + 4);
            wf[s][0] = (half8){(_Float16)a.x, (_Float16)a.y, (_Float16)a.z, (_Float16)a.w,
                               (_Float16)b.x, (_Float16)b.y, (_Float16)b.z, (_Float16)b.w};
            const float* wp1 = wp0 + (size_t)16 * KW;
            float4 c = *(const float4*)(wp1);
            float4 d = *(const float4*)(wp1 + 4);
            wf[s][1] = (half8){(_Float16)c.x, (_Float16)c.y, (_Float16)c.z, (_Float16)c.w,
                               (_Float16)d.x, (_Float16)d.y, (_Float16)d.z, (_Float16)d.w};
        }
    }

    // ---- stage: f16 tile + exact-f32 channel partials, one pass (R9) ----
    const float* inb = in + (size_t)bimg * (H_IN * W_IN * C_IN);
    for (int i = tid; i < TW * TW * (C_IN / 4); i += BLOCK) {
        int cv = i & 3;
        int pp = i >> 2;
        int x = pp % TW, y = pp / TW;
        int gy = oy + y, gx = ox + x;
        float4 v = make_float4(0.f, 0.f, 0.f, 0.f);
        if (gy < H_IN && gx < W_IN)
            v = *(const float4*)(inb + ((size_t)(gy * W_IN + gx) * C_IN) + 4 * cv);
        half4v h = {(_Float16)v.x, (_Float16)v.y, (_Float16)v.z, (_Float16)v.w};
        *(half4v*)(&s_inh[pp * SINH + 4 * cv]) = h;
        s_part[pp * 4 + cv] = (v.x + v.y) + (v.z + v.w);
    }
    __syncthreads();

    // ---- angle (threads 0..63): exact-f32 intensity window, algebraic cos/sin (R9) ----
    if (tid < 64) {
        const int alx = tid & 7, aly = tid >> 3;
        float tot = EPSF, cr = 0.f, cc = 0.f;
        #pragma unroll
        for (int dy = 0; dy < KS; ++dy)
            #pragma unroll
            for (int dx = 0; dx < KS; ++dx) {
                float4 pv = *(const float4*)(&s_part[((aly + dy) * TW + (alx + dx)) * 4]);
                float v = (pv.x + pv.y) + (pv.z + pv.w);
                tot += v; cr += v * (float)dy; cc += v * (float)dx;
            }
        cr /= tot; cc /= tot;
        float dyv = cr - 2.0f, dxv = cc - 2.0f + EPSF;
        float r = sqrtf(dxv * dxv + dyv * dyv);
        float co, si;
        if (r < 1e-20f) { co = 1.f; si = 0.f; }     // atan2(0,+0) = 0
        else           { float ri = 1.0f / r; co = dxv * ri; si = dyv * ri; }
        float xoff = (4.0f - (co * 4.0f - si * 4.0f)) * 0.5f;
        float yoff = (4.0f - (si * 4.0f + co * 4.0f)) * 0.5f;
        s_ang4[tid] = make_float4(co, si, xoff, yoff);
    }
    __syncthreads();

    // hoist per-m rotation params (pixel 16m+col) into registers
    float4 angs[4];
    #pragma unroll
    for (int m = 0; m < 4; ++m) angs[m] = s_ang4[16 * m + col];

    // ---- split-K: wave wv owns taps {wv, wv+4, ...}; step s = (wv+8s, wv+8s+4)
    floatx4 acc[4][2];
    #pragma unroll
    for (int m = 0; m < 4; ++m) {
        acc[m][0] = (floatx4){0.f, 0.f, 0.f, 0.f};
        acc[m][1] = acc[m][0];
    }

    const int lxq = col & 7, lyq0 = col >> 3;  // pixel 16m+col coords (lyq = 2m+lyq0)

    #pragma unroll
    for (int s = 0; s < 4; ++s) {
        if (s < nstep) {
            const int ta = wv + 8 * s;         // < 25 whenever executed
            const int tb = ta + 4;             // >= 25 only for (wv==0, s==3)
            const int tq = (quad < 2) ? ta : tb;

            // A-fragments in registers: pixel 16m+col, tap tq, ch ch0..ch0+7
            #pragma unroll
            for (int m = 0; m < 4; ++m) {
                half8 av = zero8;
                if (tq < KS * KS)
                    av = blend8h(s_inh, lxq, 2 * m + lyq0,
                                 angs[m].x, angs[m].y, angs[m].z, angs[m].w,
                                 tq, ch0);
                acc[m][0] = __builtin_amdgcn_mfma_f32_16x16x32_f16(av, wf[s][0], acc[m][0], 0, 0, 0);
                acc[m][1] = __builtin_amdgcn_mfma_f32_16x16x32_f16(av, wf[s][1], acc[m][1], 0, 0, 0);
            }
        }
    }

    // ---- cross-wave reduce (2 barriers) ----
    __syncthreads();                           // all waves done reading s_inh/s_ang
    #pragma unroll
    for (int m = 0; m < 4; ++m)
        #pragma unroll
        for (int n = 0; n < 2; ++n)
            #pragma unroll
            for (int r = 0; r < 4; ++r) {
                int px = 16 * m + 4 * quad + r;          // D: row = quad*4+reg
                red[wv * RED_WAVE + px * RED_STRIDE + n * 16 + col] = acc[m][n][r];
            }
    __syncthreads();

    // thread tid -> pixel tid>>2, f block (tid&3)*8 ; sum 4 partials + bias
    const int rpx = tid >> 2;
    const int rf0 = (tid & 3) * 8;
    float sum[8];
    #pragma unroll
    for (int j = 0; j < 8; ++j) sum[j] = bg[rf0 + j];
    #pragma unroll
    for (int w = 0; w < 4; ++w) {
        const float* rp = red + w * RED_WAVE + rpx * RED_STRIDE + rf0;
        #pragma unroll
        for (int j = 0; j < 8; ++j) sum[j] += rp[j];
    }
    const int ho = oy + (rpx >> 3), wo = ox + (rpx & 7);
    if (ho < HO && wo < WO) {
        float* op = out + (((size_t)bimg * HO + ho) * WO + wo) * F_OUT + rf0;
        *(float4*)op       = make_float4(sum[0], sum[1], sum[2], sum[3]);
        *(float4*)(op + 4) = make_float4(sum[4], sum[5], sum[6], sum[7]);
    }
}

extern "C" void kernel_launch(void* const* d_in, const int* in_sizes, int n_in,
                              void* d_out, int out_size, void* d_ws, size_t ws_size,
                              hipStream_t stream) {
    const float* in = (const float*)d_in[0];
    const float* Wg = (const float*)d_in[1];
    const float* bg = (const float*)d_in[2];
    float* out      = (float*)d_out;
    dim3 grid((WO + TILE - 1) / TILE, (HO + TILE - 1) / TILE, NBATCH);
    rotconv_kernel<<<grid, dim3(BLOCK), 0, stream>>>(in, Wg, bg, out);
}

// Round 10
// 71.318 us; speedup vs baseline: 1.0626x; 1.0394x over previous
//
#include <hip/hip_runtime.h>

// RotationalConv2D R12 = R9 restored (confirmed session-best, 71.5us).
// Ledger: R3 75.9 -> R5 74.1 (zero K-loop barriers) -> R8 73.6 (f16 MFMA
// pipeline) -> R9 71.5 (fused prologue) -> R10 75.8 (M-split: broke W-load
// amortization) -> R11 74.1 (top-of-kernel W prefetch: VGPR liveness /
// occupancy tax). Both post-R9 structural ideas regressed; reverting to the
// proven optimum.
//  - stage writes f16 tile DIRECTLY + exact-f32 channel partials (one pass)
//  - angle from partials, one ds_read_b128/tap; algebraic cos/sin (no atan2)
//  - K-loop: split-K across waves, register-direct A-frags via blend8h,
//    zero barriers; W-fragments loaded in-loop (compiler batches after
//    barrier 2 -- proven best placement)
//  - cross-wave f32 reduce + coalesced epilogue. 4 barriers total.

#define KS     5
#define TILE   8
#define TW     (TILE + KS - 1)     // 12
#define SINH   24                  // f16 tile pixel stride (halves, 48 B)
#define C_IN   16
#define F_OUT  32
#define H_IN   128
#define W_IN   128
#define HO     124
#define WO     124
#define NBATCH 4
#define EPSF   1e-7f
#define BLOCK  256
#define KW     400                 // K = 25*16

// LDS layout (bytes):
//   phase 1: s_inh [0,6912) f16 tile | s_part [6912,9216) f32 partials
//            s_ang [9216,10240)
//   phase 2 (epilogue, after barrier): red [0,34816) -- aliases everything
#define PART_OFF    6912
#define ANG_OFF     9216
#define RED_STRIDE  34             // floats per pixel row (136 B)
#define RED_WAVE    (64 * RED_STRIDE)
#define SMEM_BYTES  34816

typedef _Float16 half8  __attribute__((ext_vector_type(8)));
typedef _Float16 half4v __attribute__((ext_vector_type(4)));
typedef __attribute__((ext_vector_type(4))) float floatx4;

// Blend 8 channels [ch0, ch0+8) of tap t for pixel (lxq, lyq) -> f16 x8.
// Weights computed in f32 (exact index math), blend in packed f16. (R8/R9-proven)
static __device__ __forceinline__ half8 blend8h(
    const _Float16* __restrict__ s_inh, int lxq, int lyq,
    float co, float si, float xo, float yo, int t, int ch0)
{
    const float scl = 1.0f / (1.0f + EPSF);
    int ky = t / KS, kx = t - KS * ky;
    float sx = (co * (float)kx - si * (float)ky + xo) * scl;
    float sy = (si * (float)kx + co * (float)ky + yo) * scl;
    float fx0 = floorf(sx), fy0 = floorf(sy);
    float wx = sx - fx0, wy = sy - fy0;
    int x0 = (int)fx0, y0 = (int)fy0;
    int x1 = x0 + 1, y1 = y0 + 1;
    float vx0 = (x0 >= 0 && x0 < KS) ? 1.f : 0.f;
    float vx1 = (x1 >= 0 && x1 < KS) ? 1.f : 0.f;
    float vy0 = (y0 >= 0 && y0 < KS) ? 1.f : 0.f;
    float vy1 = (y1 >= 0 && y1 < KS) ? 1.f : 0.f;
    float w00 = (1.f - wx) * (1.f - wy) * vx0 * vy0;
    float w01 = wx * (1.f - wy) * vx1 * vy0;
    float w10 = (1.f - wx) * wy * vx0 * vy1;
    float w11 = wx * wy * vx1 * vy1;
    int cx0 = min(max(x0, 0), KS - 1), cx1 = min(max(x1, 0), KS - 1);
    int cy0 = min(max(y0, 0), KS - 1), cy1 = min(max(y1, 0), KS - 1);
    const _Float16* p00 = &s_inh[((lyq + cy0) * TW + (lxq + cx0)) * SINH + ch0];
    const _Float16* p01 = &s_inh[((lyq + cy0) * TW + (lxq + cx1)) * SINH + ch0];
    const _Float16* p10 = &s_inh[((lyq + cy1) * TW + (lxq + cx0)) * SINH + ch0];
    const _Float16* p11 = &s_inh[((lyq + cy1) * TW + (lxq + cx1)) * SINH + ch0];
    half8 a = *(const half8*)p00;
    half8 b = *(const half8*)p01;
    half8 c = *(const half8*)p10;
    half8 d = *(const half8*)p11;
    _Float16 h00 = (_Float16)w00, h01 = (_Float16)w01;
    _Float16 h10 = (_Float16)w10, h11 = (_Float16)w11;
    half8 W00 = {h00,h00,h00,h00,h00,h00,h00,h00};
    half8 W01 = {h01,h01,h01,h01,h01,h01,h01,h01};
    half8 W10 = {h10,h10,h10,h10,h10,h10,h10,h10};
    half8 W11 = {h11,h11,h11,h11,h11,h11,h11,h11};
    return a * W00 + b * W01 + c * W10 + d * W11;
}

__global__ __launch_bounds__(BLOCK, 2) void rotconv_kernel(
    const float* __restrict__ in, const float* __restrict__ Wg,
    const float* __restrict__ bg, float* __restrict__ out)
{
    __shared__ __align__(16) char smem[SMEM_BYTES];
    _Float16* s_inh  = (_Float16*)smem;
    float*    s_part = (float*)(smem + PART_OFF);
    float4*   s_ang4 = (float4*)(smem + ANG_OFF);
    float*    red    = (float*)smem;           // epilogue alias

    const int tid  = threadIdx.x;
    const int bx = blockIdx.x, by = blockIdx.y, bimg = blockIdx.z;
    const int ox = bx * TILE, oy = by * TILE;

    // ---- stage: f16 tile + exact-f32 channel partials, one pass ----
    const float* inb = in + (size_t)bimg * (H_IN * W_IN * C_IN);
    for (int i = tid; i < TW * TW * (C_IN / 4); i += BLOCK) {
        int cv = i & 3;
        int pp = i >> 2;
        int x = pp % TW, y = pp / TW;
        int gy = oy + y, gx = ox + x;
        float4 v = make_float4(0.f, 0.f, 0.f, 0.f);
        if (gy < H_IN && gx < W_IN)
            v = *(const float4*)(inb + ((size_t)(gy * W_IN + gx) * C_IN) + 4 * cv);
        half4v h = {(_Float16)v.x, (_Float16)v.y, (_Float16)v.z, (_Float16)v.w};
        *(half4v*)(&s_inh[pp * SINH + 4 * cv]) = h;
        s_part[pp * 4 + cv] = (v.x + v.y) + (v.z + v.w);
    }
    __syncthreads();

    // ---- angle (threads 0..63): exact-f32 intensity window, algebraic cos/sin ----
    if (tid < 64) {
        const int alx = tid & 7, aly = tid >> 3;
        float tot = EPSF, cr = 0.f, cc = 0.f;
        #pragma unroll
        for (int dy = 0; dy < KS; ++dy)
            #pragma unroll
            for (int dx = 0; dx < KS; ++dx) {
                float4 pv = *(const float4*)(&s_part[((aly + dy) * TW + (alx + dx)) * 4]);
                float v = (pv.x + pv.y) + (pv.z + pv.w);
                tot += v; cr += v * (float)dy; cc += v * (float)dx;
            }
        cr /= tot; cc /= tot;
        float dyv = cr - 2.0f, dxv = cc - 2.0f + EPSF;
        float r = sqrtf(dxv * dxv + dyv * dyv);
        float co, si;
        if (r < 1e-20f) { co = 1.f; si = 0.f; }     // atan2(0,+0) = 0
        else           { float ri = 1.0f / r; co = dxv * ri; si = dyv * ri; }
        float xoff = (4.0f - (co * 4.0f - si * 4.0f)) * 0.5f;
        float yoff = (4.0f - (si * 4.0f + co * 4.0f)) * 0.5f;
        s_ang4[tid] = make_float4(co, si, xoff, yoff);
    }
    __syncthreads();

    const int p    = tid & 63;     // lane
    const int wv   = tid >> 6;     // wave id 0..3
    const int col  = p & 15;       // MFMA lane&15
    const int quad = p >> 4;       // MFMA lane>>4

    // hoist per-m rotation params (pixel 16m+col) into registers
    float4 angs[4];
    #pragma unroll
    for (int m = 0; m < 4; ++m) angs[m] = s_ang4[16 * m + col];

    // ---- split-K: wave wv owns taps {wv, wv+4, ...}; step s = (wv+8s, wv+8s+4)
    floatx4 acc[4][2];
    #pragma unroll
    for (int m = 0; m < 4; ++m) {
        acc[m][0] = (floatx4){0.f, 0.f, 0.f, 0.f};
        acc[m][1] = acc[m][0];
    }

    const int nstep = (wv == 0) ? 4 : 3;       // wave 0 also covers tap 24
    const int lxq = col & 7, lyq0 = col >> 3;  // pixel 16m+col coords (lyq = 2m+lyq0)
    const int ch0 = (quad & 1) * 8;            // this lane's channel half
    const half8 zero8 = {0,0,0,0,0,0,0,0};

    #pragma unroll
    for (int s = 0; s < 4; ++s) {
        if (s < nstep) {
            const int ta = wv + 8 * s;         // < 25 whenever executed
            const int tb = ta + 4;             // >= 25 only for (wv==0, s==3)
            const int tq = (quad < 2) ? ta : tb;

            // B-fragment: lane holds B[8*quad+j][col] = W[f][tq*16 + ch0 + j]
            half8 bf0 = zero8, bf1 = zero8;
            if (tq < KS * KS) {
                const float* wp0 = Wg + (size_t)col * KW + tq * 16 + ch0;
                float4 a = *(const float4*)(wp0);
                float4 b = *(const float4*)(wp0 + 4);
                bf0 = (half8){(_Float16)a.x, (_Float16)a.y, (_Float16)a.z, (_Float16)a.w,
                              (_Float16)b.x, (_Float16)b.y, (_Float16)b.z, (_Float16)b.w};
                const float* wp1 = wp0 + (size_t)16 * KW;
                float4 c = *(const float4*)(wp1);
                float4 d = *(const float4*)(wp1 + 4);
                bf1 = (half8){(_Float16)c.x, (_Float16)c.y, (_Float16)c.z, (_Float16)c.w,
                              (_Float16)d.x, (_Float16)d.y, (_Float16)d.z, (_Float16)d.w};
            }

            // A-fragments in registers: pixel 16m+col, tap tq, ch ch0..ch0+7
            #pragma unroll
            for (int m = 0; m < 4; ++m) {
                half8 av = zero8;
                if (tq < KS * KS)
                    av = blend8h(s_inh, lxq, 2 * m + lyq0,
                                 angs[m].x, angs[m].y, angs[m].z, angs[m].w,
                                 tq, ch0);
                acc[m][0] = __builtin_amdgcn_mfma_f32_16x16x32_f16(av, bf0, acc[m][0], 0, 0, 0);
                acc[m][1] = __builtin_amdgcn_mfma_f32_16x16x32_f16(av, bf1, acc[m][1], 0, 0, 0);
            }
        }
    }

    // ---- cross-wave reduce (2 barriers) ----
    __syncthreads();                           // all waves done reading s_inh/s_ang
    #pragma unroll
    for (int m = 0; m < 4; ++m)
        #pragma unroll
        for (int n = 0; n < 2; ++n)
            #pragma unroll
            for (int r = 0; r < 4; ++r) {
                int px = 16 * m + 4 * quad + r;          // D: row = quad*4+reg
                red[wv * RED_WAVE + px * RED_STRIDE + n * 16 + col] = acc[m][n][r];
            }
    __syncthreads();

    // thread tid -> pixel tid>>2, f block (tid&3)*8 ; sum 4 partials + bias
    const int rpx = tid >> 2;
    const int rf0 = (tid & 3) * 8;
    float sum[8];
    #pragma unroll
    for (int j = 0; j < 8; ++j) sum[j] = bg[rf0 + j];
    #pragma unroll
    for (int w = 0; w < 4; ++w) {
        const float* rp = red + w * RED_WAVE + rpx * RED_STRIDE + rf0;
        #pragma unroll
        for (int j = 0; j < 8; ++j) sum[j] += rp[j];
    }
    const int ho = oy + (rpx >> 3), wo = ox + (rpx & 7);
    if (ho < HO && wo < WO) {
        float* op = out + (((size_t)bimg * HO + ho) * WO + wo) * F_OUT + rf0;
        *(float4*)op       = make_float4(sum[0], sum[1], sum[2], sum[3]);
        *(float4*)(op + 4) = make_float4(sum[4], sum[5], sum[6], sum[7]);
    }
}

extern "C" void kernel_launch(void* const* d_in, const int* in_sizes, int n_in,
                              void* d_out, int out_size, void* d_ws, size_t ws_size,
                              hipStream_t stream) {
    const float* in = (const float*)d_in[0];
    const float* Wg = (const float*)d_in[1];
    const float* bg = (const float*)d_in[2];
    float* out      = (float*)d_out;
    dim3 grid((WO + TILE - 1) / TILE, (HO + TILE - 1) / TILE, NBATCH);
    rotconv_kernel<<<grid, dim3(BLOCK), 0, stream>>>(in, Wg, bg, out);
}